// Round 5
// baseline (736.184 us; speedup 1.0000x reference)
//
#include <hip/hip_runtime.h>

#define DIMV 1024
#define NHV  16
#define HDV  64
#define BV   8
#define LQV  512
#define LKV  1024
#define SP   1024   // LDS score-row stride (floats): 16*1024*4 = 65536 B exact

typedef __bf16 bfrag  __attribute__((ext_vector_type(8)));
typedef float  f32x4  __attribute__((ext_vector_type(4)));
typedef unsigned short u16;
typedef unsigned int   u32;

__device__ __forceinline__ u16 f2bf(float f) {
    u32 x = __builtin_bit_cast(u32, f);
    x = x + 0x7FFFu + ((x >> 16) & 1u);   // RNE
    return (u16)(x >> 16);
}

// fp32 -> bf16 (RNE), float4-vectorized
__global__ __launch_bounds__(256)
void cast_bf(const float* __restrict__ src, u16* __restrict__ dst, int n4)
{
    const int i = blockIdx.x * 256 + threadIdx.x;
    if (i < n4) {
        const float4 v = reinterpret_cast<const float4*>(src)[i];
        ushort4 o;
        o.x = f2bf(v.x); o.y = f2bf(v.y); o.z = f2bf(v.z); o.w = f2bf(v.w);
        reinterpret_cast<ushort4*>(dst)[i] = o;
    }
}

// C[M,N] = A[M,K] @ W[N,K]^T + bias(fp32)  (K = N = 1024), A/W bf16, fp32 accum
// MODE 0: store bf16 row-major C[m*1024+n]
// MODE 1: store bf16 V^T per b:  C[((m>>10)*1024 + n)*1024 + (m&1023)]
// MODE 2: store FP32 row-major, += residual (fp32)
template<int MODE>
__global__ __launch_bounds__(256)
void gemm_nt(const u16* __restrict__ A, const u16* __restrict__ W,
             const float* __restrict__ bias, void* __restrict__ Cout,
             const float* __restrict__ resid)
{
    const int lane = threadIdx.x & 63;
    const int w    = threadIdx.x >> 6;   // 0..3
    const int quad = lane >> 4;          // 0..3
    const int r    = lane & 15;
    const int mb = blockIdx.x * 64 + (w & 1) * 32;
    const int nb = blockIdx.y * 64 + (w >> 1) * 32;

    f32x4 acc[2][2] = {};
    const int koff0 = quad * 8;
    const u16* a0p = A + (mb      + r) * DIMV + koff0;
    const u16* a1p = A + (mb + 16 + r) * DIMV + koff0;
    const u16* b0p = W + (nb      + r) * DIMV + koff0;
    const u16* b1p = W + (nb + 16 + r) * DIMV + koff0;

#pragma unroll 4
    for (int k0 = 0; k0 < DIMV; k0 += 32) {
        bfrag a0 = *reinterpret_cast<const bfrag*>(a0p + k0);
        bfrag a1 = *reinterpret_cast<const bfrag*>(a1p + k0);
        bfrag b0 = *reinterpret_cast<const bfrag*>(b0p + k0);
        bfrag b1 = *reinterpret_cast<const bfrag*>(b1p + k0);
        acc[0][0] = __builtin_amdgcn_mfma_f32_16x16x32_bf16(a0, b0, acc[0][0], 0, 0, 0);
        acc[0][1] = __builtin_amdgcn_mfma_f32_16x16x32_bf16(a0, b1, acc[0][1], 0, 0, 0);
        acc[1][0] = __builtin_amdgcn_mfma_f32_16x16x32_bf16(a1, b0, acc[1][0], 0, 0, 0);
        acc[1][1] = __builtin_amdgcn_mfma_f32_16x16x32_bf16(a1, b1, acc[1][1], 0, 0, 0);
    }

#pragma unroll
    for (int i = 0; i < 2; i++)
#pragma unroll
    for (int j = 0; j < 2; j++) {
        const int colg = nb + j * 16 + r;
        const float bv = bias[colg];
#pragma unroll
        for (int reg = 0; reg < 4; reg++) {
            const int rowg = mb + i * 16 + quad * 4 + reg;
            const float v = acc[i][j][reg] + bv;
            if (MODE == 0) {
                ((u16*)Cout)[rowg * DIMV + colg] = f2bf(v);
            } else if (MODE == 1) {
                ((u16*)Cout)[(((rowg >> 10) << 10) + colg) * LKV + (rowg & 1023)] = f2bf(v);
            } else {
                ((float*)Cout)[rowg * DIMV + colg] = v + resid[rowg * DIMV + colg];
            }
        }
    }
}

// One workgroup per (b, 16 q-rows). Loops all 16 heads; accumulates mean-prob in regs.
// attnw output is FP32.
__global__ __launch_bounds__(256)
void attn_kernel(const u16* __restrict__ q, const u16* __restrict__ k,
                 const u16* __restrict__ vT, u16* __restrict__ ctx,
                 float* __restrict__ attnw)
{
    __shared__ float sS[16 * SP];   // exactly 64 KiB

    const int t    = threadIdx.x;
    const int lane = t & 63;
    const int w    = t >> 6;
    const int quad = lane >> 4;
    const int r    = lane & 15;
    const int b    = blockIdx.y;
    const int q0   = blockIdx.x * 16;

    const int srow = t >> 4;   // softmax row 0..15 (16 consecutive lanes per row)
    const int scol = t & 15;

    float wacc[64];
#pragma unroll
    for (int i = 0; i < 64; i++) wacc[i] = 0.f;

    const float scale = 0.125f;  // 1/sqrt(64)

    for (int h = 0; h < NHV; ++h) {
        const int dbase = h * HDV + quad * 8;
        const u16* qp = q + (b * LQV + q0 + r) * DIMV + dbase;
        const bfrag qa0 = *reinterpret_cast<const bfrag*>(qp);
        const bfrag qa1 = *reinterpret_cast<const bfrag*>(qp + 32);

        // ---- S = scale * q_tile @ K^T  (16 x 1024) ----
        for (int nt = w; nt < LKV / 16; nt += 4) {
            const int n0 = nt * 16;
            const u16* kp = k + (b * LKV + n0 + r) * DIMV + dbase;
            const bfrag kb0 = *reinterpret_cast<const bfrag*>(kp);
            const bfrag kb1 = *reinterpret_cast<const bfrag*>(kp + 32);
            f32x4 s = {};
            s = __builtin_amdgcn_mfma_f32_16x16x32_bf16(qa0, kb0, s, 0, 0, 0);
            s = __builtin_amdgcn_mfma_f32_16x16x32_bf16(qa1, kb1, s, 0, 0, 0);
#pragma unroll
            for (int reg = 0; reg < 4; reg++)
                sS[(quad * 4 + reg) * SP + n0 + r] = s[reg] * scale;
        }
        __syncthreads();

        // ---- softmax over each row (16 lanes per row) ----
        float m = -1e30f;
#pragma unroll
        for (int i = 0; i < 64; i++)
            m = fmaxf(m, sS[srow * SP + scol + 16 * i]);
#pragma unroll
        for (int off = 1; off < 16; off <<= 1)
            m = fmaxf(m, __shfl_xor(m, off));

        float sum = 0.f;
#pragma unroll
        for (int i = 0; i < 64; i++) {
            const float p = __expf(sS[srow * SP + scol + 16 * i] - m);
            sS[srow * SP + scol + 16 * i] = p;
            sum += p;
        }
#pragma unroll
        for (int off = 1; off < 16; off <<= 1)
            sum += __shfl_xor(sum, off);
        const float inv = 1.0f / sum;

#pragma unroll
        for (int i = 0; i < 64; i++) {
            const float p = sS[srow * SP + scol + 16 * i] * inv;
            sS[srow * SP + scol + 16 * i] = p;
            wacc[i] += p;
        }
        __syncthreads();

        // ---- ctx_tile(16 x 64) = P(16 x 1024) @ V ; wave w owns hd cols [16w,16w+16) ----
        {
            const int n0 = w * 16;
            f32x4 c = {};
            const u16* vb = vT + (b * DIMV + h * HDV + n0 + r) * LKV;
            for (int kk = 0; kk < LKV; kk += 32) {
                union { u16 us[8]; bfrag v; } af;
#pragma unroll
                for (int j = 0; j < 8; j++)
                    af.us[j] = f2bf(sS[r * SP + kk + quad * 8 + j]);
                const bfrag bfv = *reinterpret_cast<const bfrag*>(vb + kk + quad * 8);
                c = __builtin_amdgcn_mfma_f32_16x16x32_bf16(af.v, bfv, c, 0, 0, 0);
            }
#pragma unroll
            for (int reg = 0; reg < 4; reg++) {
                const int rowg = q0 + quad * 4 + reg;
                ctx[(b * LQV + rowg) * DIMV + h * HDV + n0 + r] = f2bf(c[reg]);
            }
        }
        __syncthreads();  // protect sS before next head's QK writes
    }

    // ---- attn_weights = mean over heads (fp32 out) ----
    const float inv16 = 1.0f / 16.0f;
#pragma unroll
    for (int i = 0; i < 64; i++)
        attnw[(b * LQV + q0 + srow) * LKV + scol + 16 * i] = wacc[i] * inv16;
}

// LayerNorm per row of 1024; x fp32 (attended+residual), g/b fp32, out FP32
__global__ __launch_bounds__(256)
void ln_kernel(const float* __restrict__ x, const float* __restrict__ g,
               const float* __restrict__ bta, float* __restrict__ out)
{
    __shared__ float red[8];
    const int row = blockIdx.x;
    const int t = threadIdx.x;
    const int w = t >> 6;
    const float4 xv = reinterpret_cast<const float4*>(x + (size_t)row * DIMV)[t];

    float s = xv.x + xv.y + xv.z + xv.w;
#pragma unroll
    for (int off = 32; off; off >>= 1) s += __shfl_down(s, off);
    if ((t & 63) == 0) red[w] = s;
    __syncthreads();
    const float mu = (red[0] + red[1] + red[2] + red[3]) * (1.0f / 1024.0f);

    const float d0 = xv.x - mu, d1 = xv.y - mu, d2 = xv.z - mu, d3 = xv.w - mu;
    float s2 = d0 * d0 + d1 * d1 + d2 * d2 + d3 * d3;
#pragma unroll
    for (int off = 32; off; off >>= 1) s2 += __shfl_down(s2, off);
    if ((t & 63) == 0) red[4 + w] = s2;
    __syncthreads();
    const float var = (red[4] + red[5] + red[6] + red[7]) * (1.0f / 1024.0f);
    const float inv = rsqrtf(var + 1e-5f);

    float4 o;
    const int c = t * 4;
    o.x = d0 * inv * g[c + 0] + bta[c + 0];
    o.y = d1 * inv * g[c + 1] + bta[c + 1];
    o.z = d2 * inv * g[c + 2] + bta[c + 2];
    o.w = d3 * inv * g[c + 3] + bta[c + 3];
    reinterpret_cast<float4*>(out + (size_t)row * DIMV)[t] = o;
}

extern "C" void kernel_launch(void* const* d_in, const int* in_sizes, int n_in,
                              void* d_out, int out_size, void* d_ws, size_t ws_size,
                              hipStream_t stream)
{
    // fp32 inputs AND fp32 outputs (reference dtypes)
    const float* text = (const float*)d_in[0];   // (8,512,1024)
    const float* vis  = (const float*)d_in[1];   // (8,1024,1024)
    const float* wqkv = (const float*)d_in[2];   // (3072,1024)
    const float* bqkv = (const float*)d_in[3];   // (3072,)
    const float* outw = (const float*)d_in[4];   // (1024,1024)
    const float* outb = (const float*)d_in[5];   // (1024,)
    const float* lng  = (const float*)d_in[6];   // (1024,)
    const float* lnb  = (const float*)d_in[7];   // (1024,)

    // Workspace: exactly 64 MiB via liveness overlays.
    //  0-16M : vis_bf   (st0 w; st2,3 r)   -> 0-8M reused as ctxb (st4 w; st5 r)
    // 16-22M : wqkv_bf  (st0 w; st1-3 r)
    // 22-24M : outw_bf  (st0 w; st5 r)
    // 24-32M : qb       (st1 w; st4 r)
    // 32-40M : text_bf  (st0 w; st1 r)     -> 32-48M kb (st2 w; st4 r) -> 32-48M attb f32 (st5 w; st6 r)
    // 48-64M : vTb      (st3 w; st4 r)
    char* ws = (char*)d_ws;
    u16*   vis_bf  = (u16*)(ws);
    u16*   ctxb    = (u16*)(ws);
    u16*   wqkv_bf = (u16*)(ws + (size_t)(16u << 20));
    u16*   outw_bf = (u16*)(ws + (size_t)(22u << 20));
    u16*   qb      = (u16*)(ws + (size_t)(24u << 20));
    u16*   text_bf = (u16*)(ws + (size_t)(32u << 20));
    u16*   kb      = (u16*)(ws + (size_t)(32u << 20));
    float* attb    = (float*)(ws + (size_t)(32u << 20));
    u16*   vTb     = (u16*)(ws + (size_t)(48u << 20));

    float* outp  = (float*)d_out;                 // fp32 outputs, concat (out, attn_weights)
    float* attnw = outp + (size_t)4096 * 1024;

    const dim3 blk(256);
    // stage 0: fp32 -> bf16 casts
    cast_bf<<<dim3(8192), blk, 0, stream>>>(vis,  vis_bf,  8388608 / 4);
    cast_bf<<<dim3(3072), blk, 0, stream>>>(wqkv, wqkv_bf, 3145728 / 4);
    cast_bf<<<dim3(1024), blk, 0, stream>>>(outw, outw_bf, 1048576 / 4);
    cast_bf<<<dim3(4096), blk, 0, stream>>>(text, text_bf, 4194304 / 4);

    // stage 1: Q = text @ Wq^T + bq
    gemm_nt<0><<<dim3(64, 16), blk, 0, stream>>>(text_bf, wqkv_bf, bqkv, qb, nullptr);
    // stage 2: K = vision @ Wk^T + bk   (overwrites text_bf region)
    gemm_nt<0><<<dim3(128, 16), blk, 0, stream>>>(vis_bf, wqkv_bf + DIMV * DIMV, bqkv + DIMV, kb, nullptr);
    // stage 3: V^T = (vision @ Wv^T + bv) transposed per b
    gemm_nt<1><<<dim3(128, 16), blk, 0, stream>>>(vis_bf, wqkv_bf + 2 * DIMV * DIMV, bqkv + 2 * DIMV, vTb, nullptr);
    // stage 4: attention + mean attn weights (fp32)  (ctxb overwrites vis_bf)
    attn_kernel<<<dim3(32, 8), blk, 0, stream>>>(qb, kb, vTb, ctxb, attnw);
    // stage 5: attended = ctx @ out_w^T + out_b + text (fp32), over dead kb
    gemm_nt<2><<<dim3(64, 16), blk, 0, stream>>>(ctxb, outw_bf, outb, attb, text);
    // stage 6: layernorm -> out (fp32)
    ln_kernel<<<dim3(4096), blk, 0, stream>>>(attb, lng, lnb, outp);
}

// Round 6
// 556.201 us; speedup vs baseline: 1.3236x; 1.3236x over previous
//
#include <hip/hip_runtime.h>

#define DIMV 1024
#define NHV  16
#define HDV  64
#define BV   8
#define LQV  512
#define LKV  1024
#define PSTR 1032   // sP row stride in bf16: 2064B/row -> dword bank offset 4/row -> 2-way max (free)

typedef __bf16 bfrag  __attribute__((ext_vector_type(8)));
typedef float  f32x4  __attribute__((ext_vector_type(4)));
typedef unsigned short u16;
typedef unsigned int   u32;

__device__ __forceinline__ u16 f2bf(float f) {
    u32 x = __builtin_bit_cast(u32, f);
    x = x + 0x7FFFu + ((x >> 16) & 1u);   // RNE
    return (u16)(x >> 16);
}

// fp32 -> bf16 (RNE), float4-vectorized
__global__ __launch_bounds__(256)
void cast_bf(const float* __restrict__ src, u16* __restrict__ dst, int n4)
{
    const int i = blockIdx.x * 256 + threadIdx.x;
    if (i < n4) {
        const float4 v = reinterpret_cast<const float4*>(src)[i];
        ushort4 o;
        o.x = f2bf(v.x); o.y = f2bf(v.y); o.z = f2bf(v.z); o.w = f2bf(v.w);
        reinterpret_cast<ushort4*>(dst)[i] = o;
    }
}

// C[M,N] = A[M,K] @ W[N,K]^T + bias(fp32)  (K = N = 1024), A/W bf16, fp32 accum
// Block tile 64(M) x 128(N); wave tile 32x64.
// MODE 0: store bf16 row-major C[m*1024+n]
// MODE 1: store bf16 V^T per b:  C[((m>>10)*1024 + n)*1024 + (m&1023)]
// MODE 2: store FP32 row-major, += residual (fp32)
template<int MODE>
__global__ __launch_bounds__(256)
void gemm_nt(const u16* __restrict__ A, const u16* __restrict__ W,
             const float* __restrict__ bias, void* __restrict__ Cout,
             const float* __restrict__ resid)
{
    const int lane = threadIdx.x & 63;
    const int w    = threadIdx.x >> 6;   // 0..3
    const int quad = lane >> 4;          // 0..3
    const int r    = lane & 15;
    const int mb = blockIdx.x * 64  + (w & 1)  * 32;
    const int nb = blockIdx.y * 128 + (w >> 1) * 64;

    f32x4 acc[2][4] = {};
    const int koff0 = quad * 8;
    const u16* a0p = A + (mb      + r) * DIMV + koff0;
    const u16* a1p = A + (mb + 16 + r) * DIMV + koff0;
    const u16* bp0 = W + (nb      + r) * DIMV + koff0;
    const u16* bp1 = W + (nb + 16 + r) * DIMV + koff0;
    const u16* bp2 = W + (nb + 32 + r) * DIMV + koff0;
    const u16* bp3 = W + (nb + 48 + r) * DIMV + koff0;

#pragma unroll 2
    for (int k0 = 0; k0 < DIMV; k0 += 32) {
        bfrag a0 = *reinterpret_cast<const bfrag*>(a0p + k0);
        bfrag a1 = *reinterpret_cast<const bfrag*>(a1p + k0);
        bfrag b0 = *reinterpret_cast<const bfrag*>(bp0 + k0);
        bfrag b1 = *reinterpret_cast<const bfrag*>(bp1 + k0);
        bfrag b2 = *reinterpret_cast<const bfrag*>(bp2 + k0);
        bfrag b3 = *reinterpret_cast<const bfrag*>(bp3 + k0);
        acc[0][0] = __builtin_amdgcn_mfma_f32_16x16x32_bf16(a0, b0, acc[0][0], 0, 0, 0);
        acc[0][1] = __builtin_amdgcn_mfma_f32_16x16x32_bf16(a0, b1, acc[0][1], 0, 0, 0);
        acc[0][2] = __builtin_amdgcn_mfma_f32_16x16x32_bf16(a0, b2, acc[0][2], 0, 0, 0);
        acc[0][3] = __builtin_amdgcn_mfma_f32_16x16x32_bf16(a0, b3, acc[0][3], 0, 0, 0);
        acc[1][0] = __builtin_amdgcn_mfma_f32_16x16x32_bf16(a1, b0, acc[1][0], 0, 0, 0);
        acc[1][1] = __builtin_amdgcn_mfma_f32_16x16x32_bf16(a1, b1, acc[1][1], 0, 0, 0);
        acc[1][2] = __builtin_amdgcn_mfma_f32_16x16x32_bf16(a1, b2, acc[1][2], 0, 0, 0);
        acc[1][3] = __builtin_amdgcn_mfma_f32_16x16x32_bf16(a1, b3, acc[1][3], 0, 0, 0);
    }

#pragma unroll
    for (int i = 0; i < 2; i++)
#pragma unroll
    for (int j = 0; j < 4; j++) {
        const int colg = nb + j * 16 + r;
        const float bv = bias[colg];
#pragma unroll
        for (int reg = 0; reg < 4; reg++) {
            const int rowg = mb + i * 16 + quad * 4 + reg;
            const float v = acc[i][j][reg] + bv;
            if (MODE == 0) {
                ((u16*)Cout)[rowg * DIMV + colg] = f2bf(v);
            } else if (MODE == 1) {
                ((u16*)Cout)[(((rowg >> 10) << 10) + colg) * LKV + (rowg & 1023)] = f2bf(v);
            } else {
                ((float*)Cout)[rowg * DIMV + colg] = v + resid[rowg * DIMV + colg];
            }
        }
    }
}

// Attention v2: scores in registers, softmax via shuffles + tiny LDS cross-wave reduce,
// normalized P written as bf16 to padded LDS, PV A-frags via ds_read_b128.
// Grid (32 qtiles, 8 b, 2 head-groups); each block does 8 heads; attnw via atomicAdd.
__global__ __launch_bounds__(256, 2)
void attn_kernel(const u16* __restrict__ q, const u16* __restrict__ k,
                 const u16* __restrict__ vT, u16* __restrict__ ctx,
                 float* __restrict__ attnw)
{
    __shared__ __align__(16) u16 sP[16 * PSTR];   // 33024 B
    __shared__ float redm[64];
    __shared__ float reds[64];

    const int t    = threadIdx.x;
    const int lane = t & 63;
    const int w    = t >> 6;          // 0..3
    const int quad = lane >> 4;       // 0..3
    const int r    = lane & 15;
    const int b    = blockIdx.y;
    const int q0   = blockIdx.x * 16;
    const int hg   = blockIdx.z;      // 0..1

    const int row16 = quad * 4;       // lane's first C-row
    const float scale = 0.125f;       // 1/sqrt(64)

    f32x4 wacc[16] = {};              // (i, reg) -> prob sum over this block's heads

    for (int hh = 0; hh < 8; ++hh) {
        const int h = hg * 8 + hh;
        const int dbase = h * HDV + quad * 8;

        const u16* qp = q + (b * LQV + q0 + r) * DIMV + dbase;
        const bfrag qa0 = *reinterpret_cast<const bfrag*>(qp);
        const bfrag qa1 = *reinterpret_cast<const bfrag*>(qp + 32);

        // ---- QK: wave w covers columns [256w, 256w+256), 16 tiles, scores in regs ----
        f32x4 s[16];
#pragma unroll
        for (int i = 0; i < 16; ++i) {
            const int n0 = w * 256 + i * 16;
            const u16* kp = k + (b * LKV + n0 + r) * DIMV + dbase;
            const bfrag kb0 = *reinterpret_cast<const bfrag*>(kp);
            const bfrag kb1 = *reinterpret_cast<const bfrag*>(kp + 32);
            f32x4 acc = {};
            acc  = __builtin_amdgcn_mfma_f32_16x16x32_bf16(qa0, kb0, acc, 0, 0, 0);
            s[i] = __builtin_amdgcn_mfma_f32_16x16x32_bf16(qa1, kb1, acc, 0, 0, 0);
        }

        // ---- row max (per lane over its 16 cols, then 16-lane group, then cross-wave) ----
        float mymax[4] = {-1e30f, -1e30f, -1e30f, -1e30f};
#pragma unroll
        for (int i = 0; i < 16; ++i)
#pragma unroll
            for (int reg = 0; reg < 4; ++reg) {
                s[i][reg] *= scale;
                mymax[reg] = fmaxf(mymax[reg], s[i][reg]);
            }
#pragma unroll
        for (int reg = 0; reg < 4; ++reg)
#pragma unroll
            for (int off = 1; off < 16; off <<= 1)
                mymax[reg] = fmaxf(mymax[reg], __shfl_xor(mymax[reg], off));
        if (r == 0) {
#pragma unroll
            for (int reg = 0; reg < 4; ++reg) redm[w * 16 + row16 + reg] = mymax[reg];
        }
        __syncthreads();
        float rowm[4];
#pragma unroll
        for (int reg = 0; reg < 4; ++reg)
            rowm[reg] = fmaxf(fmaxf(redm[row16 + reg], redm[16 + row16 + reg]),
                              fmaxf(redm[32 + row16 + reg], redm[48 + row16 + reg]));

        // ---- exp + row sum ----
        float mysum[4] = {0.f, 0.f, 0.f, 0.f};
#pragma unroll
        for (int i = 0; i < 16; ++i)
#pragma unroll
            for (int reg = 0; reg < 4; ++reg) {
                s[i][reg] = __expf(s[i][reg] - rowm[reg]);
                mysum[reg] += s[i][reg];
            }
#pragma unroll
        for (int reg = 0; reg < 4; ++reg)
#pragma unroll
            for (int off = 1; off < 16; off <<= 1)
                mysum[reg] += __shfl_xor(mysum[reg], off);
        if (r == 0) {
#pragma unroll
            for (int reg = 0; reg < 4; ++reg) reds[w * 16 + row16 + reg] = mysum[reg];
        }
        __syncthreads();
        float inv[4];
#pragma unroll
        for (int reg = 0; reg < 4; ++reg)
            inv[reg] = 1.0f / (reds[row16 + reg] + reds[16 + row16 + reg] +
                               reds[32 + row16 + reg] + reds[48 + row16 + reg]);

        // ---- normalize, accumulate mean-prob, write bf16 P to LDS ----
#pragma unroll
        for (int i = 0; i < 16; ++i)
#pragma unroll
            for (int reg = 0; reg < 4; ++reg) {
                const float pn = s[i][reg] * inv[reg];
                wacc[i][reg] += pn;
                sP[(row16 + reg) * PSTR + w * 256 + i * 16 + r] = f2bf(pn);
            }
        __syncthreads();

        // ---- PV: wave w owns hd cols [16w, 16w+16); A-frag = ds_read_b128 of P ----
        {
            const int n0 = w * 16;
            f32x4 c = {};
            const u16* vb = vT + (b * DIMV + h * HDV + n0 + r) * LKV;
#pragma unroll 4
            for (int kk = 0; kk < LKV; kk += 32) {
                const bfrag af = *reinterpret_cast<const bfrag*>(&sP[r * PSTR + kk + quad * 8]);
                const bfrag bv = *reinterpret_cast<const bfrag*>(vb + kk + quad * 8);
                c = __builtin_amdgcn_mfma_f32_16x16x32_bf16(af, bv, c, 0, 0, 0);
            }
#pragma unroll
            for (int reg = 0; reg < 4; ++reg)
                ctx[(b * LQV + q0 + row16 + reg) * DIMV + h * HDV + n0 + r] = f2bf(c[reg]);
        }
        __syncthreads();   // sP / redm / reds safe for next head
    }

    // ---- attn_weights mean: add this block's 8-head sum (attnw pre-zeroed) ----
    const float inv16 = 1.0f / 16.0f;
#pragma unroll
    for (int i = 0; i < 16; ++i)
#pragma unroll
        for (int reg = 0; reg < 4; ++reg)
            atomicAdd(&attnw[(b * LQV + q0 + row16 + reg) * LKV + w * 256 + i * 16 + r],
                      wacc[i][reg] * inv16);
}

// LayerNorm per row of 1024; x fp32 (attended+residual), g/b fp32, out FP32
__global__ __launch_bounds__(256)
void ln_kernel(const float* __restrict__ x, const float* __restrict__ g,
               const float* __restrict__ bta, float* __restrict__ out)
{
    __shared__ float red[8];
    const int row = blockIdx.x;
    const int t = threadIdx.x;
    const int w = t >> 6;
    const float4 xv = reinterpret_cast<const float4*>(x + (size_t)row * DIMV)[t];

    float s = xv.x + xv.y + xv.z + xv.w;
#pragma unroll
    for (int off = 32; off; off >>= 1) s += __shfl_down(s, off);
    if ((t & 63) == 0) red[w] = s;
    __syncthreads();
    const float mu = (red[0] + red[1] + red[2] + red[3]) * (1.0f / 1024.0f);

    const float d0 = xv.x - mu, d1 = xv.y - mu, d2 = xv.z - mu, d3 = xv.w - mu;
    float s2 = d0 * d0 + d1 * d1 + d2 * d2 + d3 * d3;
#pragma unroll
    for (int off = 32; off; off >>= 1) s2 += __shfl_down(s2, off);
    if ((t & 63) == 0) red[4 + w] = s2;
    __syncthreads();
    const float var = (red[4] + red[5] + red[6] + red[7]) * (1.0f / 1024.0f);
    const float inv = rsqrtf(var + 1e-5f);

    float4 o;
    const int c = t * 4;
    o.x = d0 * inv * g[c + 0] + bta[c + 0];
    o.y = d1 * inv * g[c + 1] + bta[c + 1];
    o.z = d2 * inv * g[c + 2] + bta[c + 2];
    o.w = d3 * inv * g[c + 3] + bta[c + 3];
    reinterpret_cast<float4*>(out + (size_t)row * DIMV)[t] = o;
}

extern "C" void kernel_launch(void* const* d_in, const int* in_sizes, int n_in,
                              void* d_out, int out_size, void* d_ws, size_t ws_size,
                              hipStream_t stream)
{
    const float* text = (const float*)d_in[0];   // (8,512,1024)
    const float* vis  = (const float*)d_in[1];   // (8,1024,1024)
    const float* wqkv = (const float*)d_in[2];   // (3072,1024)
    const float* bqkv = (const float*)d_in[3];   // (3072,)
    const float* outw = (const float*)d_in[4];   // (1024,1024)
    const float* outb = (const float*)d_in[5];   // (1024,)
    const float* lng  = (const float*)d_in[6];   // (1024,)
    const float* lnb  = (const float*)d_in[7];   // (1024,)

    // Workspace: exactly 64 MiB via liveness overlays (same as passing round 5).
    char* ws = (char*)d_ws;
    u16*   vis_bf  = (u16*)(ws);                          // 0-16M
    u16*   ctxb    = (u16*)(ws);                          // 0-8M   (st4 w; st5 r)
    u16*   wqkv_bf = (u16*)(ws + (size_t)(16u << 20));    // 16-22M
    u16*   outw_bf = (u16*)(ws + (size_t)(22u << 20));    // 22-24M
    u16*   qb      = (u16*)(ws + (size_t)(24u << 20));    // 24-32M
    u16*   text_bf = (u16*)(ws + (size_t)(32u << 20));    // 32-40M (dead after st1)
    u16*   kb      = (u16*)(ws + (size_t)(32u << 20));    // 32-48M
    float* attb    = (float*)(ws + (size_t)(32u << 20));  // 32-48M (st5 w; st6 r)
    u16*   vTb     = (u16*)(ws + (size_t)(48u << 20));    // 48-64M

    float* outp  = (float*)d_out;                 // fp32 outputs, concat (out, attn_weights)
    float* attnw = outp + (size_t)4096 * 1024;

    const dim3 blk(256);
    // stage 0: fp32 -> bf16 casts
    cast_bf<<<dim3(8192), blk, 0, stream>>>(vis,  vis_bf,  8388608 / 4);
    cast_bf<<<dim3(3072), blk, 0, stream>>>(wqkv, wqkv_bf, 3145728 / 4);
    cast_bf<<<dim3(1024), blk, 0, stream>>>(outw, outw_bf, 1048576 / 4);
    cast_bf<<<dim3(4096), blk, 0, stream>>>(text, text_bf, 4194304 / 4);

    // stage 1: Q = text @ Wq^T + bq
    gemm_nt<0><<<dim3(64, 8), blk, 0, stream>>>(text_bf, wqkv_bf, bqkv, qb, nullptr);
    // stage 2: K = vision @ Wk^T + bk   (overwrites text_bf region)
    gemm_nt<0><<<dim3(128, 8), blk, 0, stream>>>(vis_bf, wqkv_bf + DIMV * DIMV, bqkv + DIMV, kb, nullptr);
    // stage 3: V^T = (vision @ Wv^T + bv) transposed per b
    gemm_nt<1><<<dim3(128, 8), blk, 0, stream>>>(vis_bf, wqkv_bf + 2 * DIMV * DIMV, bqkv + 2 * DIMV, vTb, nullptr);
    // stage 4: attention; attnw zero-init then atomic mean-accumulate
    hipMemsetAsync(attnw, 0, (size_t)4096 * 1024 * sizeof(float), stream);
    attn_kernel<<<dim3(32, 8, 2), blk, 0, stream>>>(qb, kb, vTb, ctxb, attnw);
    // stage 5: attended = ctx @ out_w^T + out_b + text (fp32), over dead kb
    gemm_nt<2><<<dim3(64, 8), blk, 0, stream>>>(ctxb, outw_bf, outb, attb, text);
    // stage 6: layernorm -> out (fp32)
    ln_kernel<<<dim3(4096), blk, 0, stream>>>(attb, lng, lnb, outp);
}

// Round 7
// 401.618 us; speedup vs baseline: 1.8330x; 1.3849x over previous
//
#include <hip/hip_runtime.h>

#define DIMV 1024
#define NHV  16
#define HDV  64
#define BV   8
#define LQV  512
#define LKV  1024
#define PSTR 1032   // sP row stride in bf16: 2064B/row -> 2-way banks max (free)

typedef __bf16 bfrag  __attribute__((ext_vector_type(8)));
typedef float  f32x4  __attribute__((ext_vector_type(4)));
typedef unsigned short u16;
typedef unsigned int   u32;
typedef unsigned long long u64;

typedef const __attribute__((address_space(1))) u32 gu32;
typedef __attribute__((address_space(3))) u32 lu32;

__device__ __forceinline__ u16 f2bf(float f) {
    u32 x = __builtin_bit_cast(u32, f);
    x = x + 0x7FFFu + ((x >> 16) & 1u);   // RNE
    return (u16)(x >> 16);
}

// async global->LDS, 16B per lane; LDS dest must be wave-uniform base (+lane*16 implicit)
__device__ __forceinline__ void g2l16(const u16* g, const u16* l) {
    __builtin_amdgcn_global_load_lds(
        reinterpret_cast<gu32*>(reinterpret_cast<u64>(g)),
        reinterpret_cast<lu32*>((u32)reinterpret_cast<u64>(l)),
        16, 0, 0);
}

// fp32 -> bf16 (RNE), float4-vectorized
__global__ __launch_bounds__(256)
void cast_bf(const float* __restrict__ src, u16* __restrict__ dst, int n4)
{
    const int i = blockIdx.x * 256 + threadIdx.x;
    if (i < n4) {
        const float4 v = reinterpret_cast<const float4*>(src)[i];
        ushort4 o;
        o.x = f2bf(v.x); o.y = f2bf(v.y); o.z = f2bf(v.z); o.w = f2bf(v.w);
        reinterpret_cast<ushort4*>(dst)[i] = o;
    }
}

// C[M,N] = A[M,K] @ W[N,K]^T + bias(fp32), K=N=1024, bf16 in, fp32 accum.
// m97-style: 128x128 block tile, BK=64, global_load_lds staging, 4 waves 2x2, 4x4 acc.
// MODE 0: bf16 row-major; MODE 1: bf16 V^T per b; MODE 2: fp32 + residual
template<int MODE>
__global__ __launch_bounds__(256)
void gemm_nt(const u16* __restrict__ A, const u16* __restrict__ W,
             const float* __restrict__ bias, void* __restrict__ Cout,
             const float* __restrict__ resid)
{
    __shared__ __align__(16) u16 sA[128 * 64];
    __shared__ __align__(16) u16 sB[128 * 64];

    const int t    = threadIdx.x;
    const int lane = t & 63;
    const int w    = t >> 6;
    const int quad = lane >> 4;
    const int r    = lane & 15;
    const int wr   = (w >> 1) * 64;   // wave row offset in tile
    const int wc   = (w & 1) * 64;    // wave col offset
    const int mb   = blockIdx.x * 128;
    const int nb   = blockIdx.y * 128;

    const int srow  = lane >> 3;        // 0..7 row within 8-row chunk
    const int skoff = (lane & 7) * 8;   // k element offset

    f32x4 acc[4][4] = {};

    const u16* Abase = A + (size_t)mb * 1024 + skoff;
    const u16* Wbase = W + (size_t)nb * 1024 + skoff;

    for (int k0 = 0; k0 < 1024; k0 += 64) {
        // stage A/B tiles (128x64 each): wave w stages chunks w*4..w*4+3 (8 rows each)
#pragma unroll
        for (int it = 0; it < 4; ++it) {
            const int c = w * 4 + it;
            const int row = c * 8 + srow;
            g2l16(Abase + (size_t)row * 1024 + k0, sA + c * 512);
            g2l16(Wbase + (size_t)row * 1024 + k0, sB + c * 512);
        }
        __syncthreads();   // drains vmcnt (async LDS loads) + barrier
#pragma unroll
        for (int kk = 0; kk < 2; ++kk) {
            bfrag af[4], bg[4];
#pragma unroll
            for (int i = 0; i < 4; ++i)
                af[i] = *reinterpret_cast<const bfrag*>(sA + (wr + i * 16 + r) * 64 + kk * 32 + quad * 8);
#pragma unroll
            for (int j = 0; j < 4; ++j)
                bg[j] = *reinterpret_cast<const bfrag*>(sB + (wc + j * 16 + r) * 64 + kk * 32 + quad * 8);
#pragma unroll
            for (int i = 0; i < 4; ++i)
#pragma unroll
                for (int j = 0; j < 4; ++j)
                    acc[i][j] = __builtin_amdgcn_mfma_f32_16x16x32_bf16(af[i], bg[j], acc[i][j], 0, 0, 0);
        }
        __syncthreads();   // all reads done before restage
    }

#pragma unroll
    for (int i = 0; i < 4; i++)
#pragma unroll
    for (int j = 0; j < 4; j++) {
        const int colg = nb + wc + j * 16 + r;
        const float bv = bias[colg];
#pragma unroll
        for (int reg = 0; reg < 4; reg++) {
            const int rowg = mb + wr + i * 16 + quad * 4 + reg;
            const float v = acc[i][j][reg] + bv;
            if (MODE == 0) {
                ((u16*)Cout)[(size_t)rowg * 1024 + colg] = f2bf(v);
            } else if (MODE == 1) {
                ((u16*)Cout)[((size_t)((rowg >> 10) << 10) + colg) * 1024 + (rowg & 1023)] = f2bf(v);
            } else {
                ((float*)Cout)[(size_t)rowg * 1024 + colg] = v + resid[(size_t)rowg * 1024 + colg];
            }
        }
    }
}

// Attention v3: scores in regs; ONE-barrier flash-combine softmax; bf16 P via padded LDS;
// PV as 4 independent MFMA chains. Grid (32 qtiles, 8 b, 4 head-groups), 4 heads/block.
__global__ __launch_bounds__(256, 2)
void attn_kernel(const u16* __restrict__ q, const u16* __restrict__ k,
                 const u16* __restrict__ vT, u16* __restrict__ ctx,
                 float* __restrict__ attnw)
{
    __shared__ __align__(16) u16 sP[16 * PSTR];   // 33024 B
    __shared__ float redm[64];
    __shared__ float reds[64];

    const int t    = threadIdx.x;
    const int lane = t & 63;
    const int w    = t >> 6;          // 0..3
    const int quad = lane >> 4;       // 0..3
    const int r    = lane & 15;
    const int b    = blockIdx.y;
    const int q0   = blockIdx.x * 16;
    const int hg   = blockIdx.z;      // 0..3

    const int row16 = quad * 4;
    const float scale = 0.125f;       // 1/sqrt(64)

    f32x4 wacc[16] = {};

    for (int hh = 0; hh < 4; ++hh) {
        const int h = hg * 4 + hh;
        const int dbase = h * HDV + quad * 8;

        const u16* qp = q + (size_t)(b * LQV + q0 + r) * DIMV + dbase;
        const bfrag qa0 = *reinterpret_cast<const bfrag*>(qp);
        const bfrag qa1 = *reinterpret_cast<const bfrag*>(qp + 32);

        // ---- QK: wave w covers cols [256w,256w+256), scores in regs ----
        f32x4 s[16];
#pragma unroll
        for (int i = 0; i < 16; ++i) {
            const int n0 = w * 256 + i * 16;
            const u16* kp = k + (size_t)(b * LKV + n0 + r) * DIMV + dbase;
            const bfrag kb0 = *reinterpret_cast<const bfrag*>(kp);
            const bfrag kb1 = *reinterpret_cast<const bfrag*>(kp + 32);
            f32x4 a = {};
            a    = __builtin_amdgcn_mfma_f32_16x16x32_bf16(qa0, kb0, a, 0, 0, 0);
            s[i] = __builtin_amdgcn_mfma_f32_16x16x32_bf16(qa1, kb1, a, 0, 0, 0);
        }

        // ---- wave-local max over 256 cols per row ----
        float mw[4] = {-1e30f, -1e30f, -1e30f, -1e30f};
#pragma unroll
        for (int i = 0; i < 16; ++i)
#pragma unroll
            for (int reg = 0; reg < 4; ++reg) {
                s[i][reg] *= scale;
                mw[reg] = fmaxf(mw[reg], s[i][reg]);
            }
#pragma unroll
        for (int reg = 0; reg < 4; ++reg)
#pragma unroll
            for (int off = 1; off < 16; off <<= 1)
                mw[reg] = fmaxf(mw[reg], __shfl_xor(mw[reg], off));

        // ---- exp(s - m_w) + wave-local sum ----
        float sw[4] = {0.f, 0.f, 0.f, 0.f};
#pragma unroll
        for (int i = 0; i < 16; ++i)
#pragma unroll
            for (int reg = 0; reg < 4; ++reg) {
                s[i][reg] = __expf(s[i][reg] - mw[reg]);
                sw[reg] += s[i][reg];
            }
#pragma unroll
        for (int reg = 0; reg < 4; ++reg)
#pragma unroll
            for (int off = 1; off < 16; off <<= 1)
                sw[reg] += __shfl_xor(sw[reg], off);

        if (r == 0) {
#pragma unroll
            for (int reg = 0; reg < 4; ++reg) {
                redm[w * 16 + row16 + reg] = mw[reg];
                reds[w * 16 + row16 + reg] = sw[reg];
            }
        }
        __syncthreads();   // single combine barrier

        // ---- flash combine: factor = exp(m_w - M) / total ----
        float factor[4];
#pragma unroll
        for (int reg = 0; reg < 4; ++reg) {
            const int rr = row16 + reg;
            const float m0 = redm[rr], m1 = redm[16 + rr], m2 = redm[32 + rr], m3 = redm[48 + rr];
            const float M = fmaxf(fmaxf(m0, m1), fmaxf(m2, m3));
            const float total = __expf(m0 - M) * reds[rr]      + __expf(m1 - M) * reds[16 + rr] +
                                __expf(m2 - M) * reds[32 + rr] + __expf(m3 - M) * reds[48 + rr];
            factor[reg] = __expf(mw[reg] - M) / total;
        }

        // ---- normalize, accumulate mean-prob, write bf16 P to LDS ----
#pragma unroll
        for (int i = 0; i < 16; ++i)
#pragma unroll
            for (int reg = 0; reg < 4; ++reg) {
                const float pn = s[i][reg] * factor[reg];
                wacc[i][reg] += pn;
                sP[(row16 + reg) * PSTR + w * 256 + i * 16 + r] = f2bf(pn);
            }
        __syncthreads();

        // ---- PV: wave w owns hd cols [16w,16w+16); 4 independent chains ----
        {
            const int n0 = w * 16;
            f32x4 c0 = {}, c1 = {}, c2 = {}, c3 = {};
            const u16* vb = vT + (size_t)(b * DIMV + h * HDV + n0 + r) * LKV;
#pragma unroll
            for (int kk = 0; kk < LKV; kk += 128) {
                const bfrag a0 = *reinterpret_cast<const bfrag*>(&sP[r * PSTR + kk      + quad * 8]);
                const bfrag a1 = *reinterpret_cast<const bfrag*>(&sP[r * PSTR + kk + 32 + quad * 8]);
                const bfrag a2 = *reinterpret_cast<const bfrag*>(&sP[r * PSTR + kk + 64 + quad * 8]);
                const bfrag a3 = *reinterpret_cast<const bfrag*>(&sP[r * PSTR + kk + 96 + quad * 8]);
                const bfrag b0 = *reinterpret_cast<const bfrag*>(vb + kk      + quad * 8);
                const bfrag b1 = *reinterpret_cast<const bfrag*>(vb + kk + 32 + quad * 8);
                const bfrag b2 = *reinterpret_cast<const bfrag*>(vb + kk + 64 + quad * 8);
                const bfrag b3 = *reinterpret_cast<const bfrag*>(vb + kk + 96 + quad * 8);
                c0 = __builtin_amdgcn_mfma_f32_16x16x32_bf16(a0, b0, c0, 0, 0, 0);
                c1 = __builtin_amdgcn_mfma_f32_16x16x32_bf16(a1, b1, c1, 0, 0, 0);
                c2 = __builtin_amdgcn_mfma_f32_16x16x32_bf16(a2, b2, c2, 0, 0, 0);
                c3 = __builtin_amdgcn_mfma_f32_16x16x32_bf16(a3, b3, c3, 0, 0, 0);
            }
            const f32x4 c = (c0 + c1) + (c2 + c3);
#pragma unroll
            for (int reg = 0; reg < 4; ++reg)
                ctx[(size_t)(b * LQV + q0 + row16 + reg) * DIMV + h * HDV + n0 + r] = f2bf(c[reg]);
        }
        __syncthreads();   // sP/redm/reds safe for next head
    }

    // ---- attn_weights mean: add this block's 4-head sum (attnw pre-zeroed) ----
    const float inv16 = 1.0f / 16.0f;
#pragma unroll
    for (int i = 0; i < 16; ++i)
#pragma unroll
        for (int reg = 0; reg < 4; ++reg)
            atomicAdd(&attnw[(size_t)(b * LQV + q0 + row16 + reg) * LKV + w * 256 + i * 16 + r],
                      wacc[i][reg] * inv16);
}

// LayerNorm per row of 1024; x fp32 (attended+residual), g/b fp32, out fp32
__global__ __launch_bounds__(256)
void ln_kernel(const float* __restrict__ x, const float* __restrict__ g,
               const float* __restrict__ bta, float* __restrict__ out)
{
    __shared__ float red[8];
    const int row = blockIdx.x;
    const int t = threadIdx.x;
    const int w = t >> 6;
    const float4 xv = reinterpret_cast<const float4*>(x + (size_t)row * DIMV)[t];

    float s = xv.x + xv.y + xv.z + xv.w;
#pragma unroll
    for (int off = 32; off; off >>= 1) s += __shfl_down(s, off);
    if ((t & 63) == 0) red[w] = s;
    __syncthreads();
    const float mu = (red[0] + red[1] + red[2] + red[3]) * (1.0f / 1024.0f);

    const float d0 = xv.x - mu, d1 = xv.y - mu, d2 = xv.z - mu, d3 = xv.w - mu;
    float s2 = d0 * d0 + d1 * d1 + d2 * d2 + d3 * d3;
#pragma unroll
    for (int off = 32; off; off >>= 1) s2 += __shfl_down(s2, off);
    if ((t & 63) == 0) red[4 + w] = s2;
    __syncthreads();
    const float var = (red[4] + red[5] + red[6] + red[7]) * (1.0f / 1024.0f);
    const float inv = rsqrtf(var + 1e-5f);

    float4 o;
    const int c = t * 4;
    o.x = d0 * inv * g[c + 0] + bta[c + 0];
    o.y = d1 * inv * g[c + 1] + bta[c + 1];
    o.z = d2 * inv * g[c + 2] + bta[c + 2];
    o.w = d3 * inv * g[c + 3] + bta[c + 3];
    reinterpret_cast<float4*>(out + (size_t)row * DIMV)[t] = o;
}

extern "C" void kernel_launch(void* const* d_in, const int* in_sizes, int n_in,
                              void* d_out, int out_size, void* d_ws, size_t ws_size,
                              hipStream_t stream)
{
    const float* text = (const float*)d_in[0];   // (8,512,1024)
    const float* vis  = (const float*)d_in[1];   // (8,1024,1024)
    const float* wqkv = (const float*)d_in[2];   // (3072,1024)
    const float* bqkv = (const float*)d_in[3];   // (3072,)
    const float* outw = (const float*)d_in[4];   // (1024,1024)
    const float* outb = (const float*)d_in[5];   // (1024,)
    const float* lng  = (const float*)d_in[6];   // (1024,)
    const float* lnb  = (const float*)d_in[7];   // (1024,)

    // Workspace: exactly 64 MiB via liveness overlays (as in passing rounds 5/6).
    char* ws = (char*)d_ws;
    u16*   vis_bf  = (u16*)(ws);                          // 0-16M
    u16*   ctxb    = (u16*)(ws);                          // 0-8M   (st4 w; st5 r)
    u16*   wqkv_bf = (u16*)(ws + (size_t)(16u << 20));    // 16-22M
    u16*   outw_bf = (u16*)(ws + (size_t)(22u << 20));    // 22-24M
    u16*   qb      = (u16*)(ws + (size_t)(24u << 20));    // 24-32M
    u16*   text_bf = (u16*)(ws + (size_t)(32u << 20));    // 32-40M (dead after st1)
    u16*   kb      = (u16*)(ws + (size_t)(32u << 20));    // 32-48M
    float* attb    = (float*)(ws + (size_t)(32u << 20));  // 32-48M (st5 w; st6 r)
    u16*   vTb     = (u16*)(ws + (size_t)(48u << 20));    // 48-64M

    float* outp  = (float*)d_out;                 // fp32 outputs, concat (out, attn_weights)
    float* attnw = outp + (size_t)4096 * 1024;

    const dim3 blk(256);
    // stage 0: fp32 -> bf16 casts
    cast_bf<<<dim3(8192), blk, 0, stream>>>(vis,  vis_bf,  8388608 / 4);
    cast_bf<<<dim3(3072), blk, 0, stream>>>(wqkv, wqkv_bf, 3145728 / 4);
    cast_bf<<<dim3(1024), blk, 0, stream>>>(outw, outw_bf, 1048576 / 4);
    cast_bf<<<dim3(4096), blk, 0, stream>>>(text, text_bf, 4194304 / 4);

    // stage 1: Q = text @ Wq^T + bq   (M=4096 -> 32x8 blocks)
    gemm_nt<0><<<dim3(32, 8), blk, 0, stream>>>(text_bf, wqkv_bf, bqkv, qb, nullptr);
    // stage 2: K = vision @ Wk^T + bk (M=8192 -> 64x8; overwrites text_bf)
    gemm_nt<0><<<dim3(64, 8), blk, 0, stream>>>(vis_bf, wqkv_bf + DIMV * DIMV, bqkv + DIMV, kb, nullptr);
    // stage 3: V^T = (vision @ Wv^T + bv) transposed per b
    gemm_nt<1><<<dim3(64, 8), blk, 0, stream>>>(vis_bf, wqkv_bf + 2 * DIMV * DIMV, bqkv + 2 * DIMV, vTb, nullptr);
    // stage 4: attention; attnw zero-init then atomic mean-accumulate
    hipMemsetAsync(attnw, 0, (size_t)4096 * 1024 * sizeof(float), stream);
    attn_kernel<<<dim3(32, 8, 4), blk, 0, stream>>>(qb, kb, vTb, ctxb, attnw);
    // stage 5: attended = ctx @ out_w^T + out_b + text (fp32), over dead kb
    gemm_nt<2><<<dim3(32, 8), blk, 0, stream>>>(ctxb, outw_bf, outb, attb, text);
    // stage 6: layernorm -> out (fp32)
    ln_kernel<<<dim3(4096), blk, 0, stream>>>(attb, lng, lnb, outp);
}